// Round 2
// baseline (436.156 us; speedup 1.0000x reference)
//
#include <hip/hip_runtime.h>

#define FWHT_N 4096
#define TPB 256
#define MAX_BLOCKS 1024   // 4 blocks/CU x 256 CUs resident in ONE wave of scheduling; 16 rows/block

// FWHT over 16 register-resident values, distances 1,2,4,8 (Sylvester order).
// Butterfly stages over disjoint index bits commute, so splitting the 12 bits
// into three groups of 4 (any order) reproduces H = H2^{(x)12} exactly.
__device__ __forceinline__ void fwht16(float a[16]) {
#pragma unroll
    for (int h = 1; h < 16; h <<= 1) {
#pragma unroll
        for (int i = 0; i < 16; i += 2 * h) {
#pragma unroll
            for (int j = i; j < i + h; ++j) {
                float u = a[j];
                float v = a[j + h];
                a[j]     = u + v;
                a[j + h] = u - v;
            }
        }
    }
}

// Barrier WITHOUT the compiler's vmcnt(0) drain (__syncthreads would emit
// s_waitcnt vmcnt(0) lgkmcnt(0) and force every in-flight prefetch load to
// complete — that is why the round-1 register pipeline was a no-op).
// lgkmcnt(0) before s_barrier: my wave's ds_writes are complete; the collective
// barrier then makes all waves' writes visible. Global prefetch loads stay in
// flight; the compiler inserts the vmcnt wait before xn[] is consumed.
// The "memory"-clobber asm on both sides pins LDS ops to their side of the
// barrier (rule: hipcc may otherwise hoist/sink ds ops past a raw s_barrier).
#define BARRIER_NOVM() do {                                   \
    asm volatile("s_waitcnt lgkmcnt(0)" ::: "memory");        \
    __builtin_amdgcn_s_barrier();                             \
    asm volatile("" ::: "memory");                            \
} while (0)

// LDS address map: A(i) = i ^ (((i>>6)&15) << 2).  BIJECTIVE (XOR flips only
// bits 2..5, which don't feed i>>6).
// Bank analysis (32 banks, per wave):
//  - exchange-1 b128 writes: quad starts uniform over 8 slots mod 32 -> free
//  - pass-B b32 r/w: exactly 2-way -> free (2-way is free per m136)
//  - pass-C b32 reads: exactly 2-way -> free

__global__ __launch_bounds__(TPB, 4) void fwht_rows_kernel(
        const float* __restrict__ x,
        const float* __restrict__ s,
        float* __restrict__ out,
        const int rows) {
    // Double-buffered: rows alternate buffers, so the tail barrier of the old
    // single-buffer version is gone (2 barriers/row, not 3). Buffer p^1's last
    // readers (row r-1 pass C) are separated from its next writers (row r+1
    // exchange-1) by BOTH of row r's collective barriers -> no race.
    __shared__ float lds[2][FWHT_N];

    const int t = threadIdx.x;
    const float scale = 0.015625f;  // 1/sqrt(4096)

    // s hoisted into registers once per persistent block.
    float sv[16];
#pragma unroll
    for (int k = 0; k < 4; ++k) {
        float4 ss = *(const float4*)(s + 4 * t + 1024 * k);
        sv[4 * k + 0] = ss.x;
        sv[4 * k + 1] = ss.y;
        sv[4 * k + 2] = ss.z;
        sv[4 * k + 3] = ss.w;
    }

    const int stride = gridDim.x;
    int row = blockIdx.x;

    // Software pipeline: xn[] holds the NEXT row. With BARRIER_NOVM these
    // loads now genuinely stay outstanding across the whole row body.
    float xn[16];
    if (row < rows) {
        const float* xr = x + (size_t)row * FWHT_N;
#pragma unroll
        for (int k = 0; k < 4; ++k) {
            float4 xx = *(const float4*)(xr + 4 * t + 1024 * k);
            xn[4 * k + 0] = xx.x;
            xn[4 * k + 1] = xx.y;
            xn[4 * k + 2] = xx.z;
            xn[4 * k + 3] = xx.w;
        }
    }

    int p = 0;
    for (; row < rows; row += stride) {
        float a[16];
#pragma unroll
        for (int m = 0; m < 16; ++m) a[m] = xn[m] * sv[m];

        // Issue next row's loads IMMEDIATELY after consuming xn: maximal
        // in-flight window (entire row body, crossing both barriers).
        const int nrow = row + stride;
        if (nrow < rows) {
            const float* xr = x + (size_t)nrow * FWHT_N;
#pragma unroll
            for (int k = 0; k < 4; ++k) {
                float4 xx = *(const float4*)(xr + 4 * t + 1024 * k);
                xn[4 * k + 0] = xx.x;
                xn[4 * k + 1] = xx.y;
                xn[4 * k + 2] = xx.z;
                xn[4 * k + 3] = xx.w;
            }
        }

        // ---- Pass A: idx bits {0,1,10,11}. Thread t owns idx = 4t + j + 1024k.
        fwht16(a);

        // ---- Exchange 1: four ds_write_b128 (quads stay contiguous under the
        // XOR map since j only touches bits 0..1).
#pragma unroll
        for (int k = 0; k < 4; ++k) {
            int i    = 4 * t + 1024 * k;
            int addr = i ^ (((i >> 6) & 15) << 2);
            *(float4*)(&lds[p][addr]) =
                make_float4(a[4 * k + 0], a[4 * k + 1], a[4 * k + 2], a[4 * k + 3]);
        }
        BARRIER_NOVM();

        // ---- Pass B: idx bits {2..5}. Thread owns idx = (t&3) + 4m + 64*(t>>2).
        {
            const int w    = t >> 2;
            const int base = 64 * w + (t & 3);
            const int swz  = w & 15;
#pragma unroll
            for (int m = 0; m < 16; ++m) a[m] = lds[p][base + 4 * (m ^ swz)];
            fwht16(a);
            // Same cells, same thread: no barrier between this read and write.
#pragma unroll
            for (int m = 0; m < 16; ++m) lds[p][base + 4 * (m ^ swz)] = a[m];
        }
        BARRIER_NOVM();

        // ---- Pass C: idx bits {6..9}. Thread owns idx = (t&63) + 64m + 1024*(t>>6).
        {
            const int hi = 1024 * (t >> 6);
            const int lo = t & 63;
#pragma unroll
            for (int m = 0; m < 16; ++m) a[m] = lds[p][hi + 64 * m + (lo ^ (m << 2))];
        }
        fwht16(a);

        // ---- Scale and store: out[(t&63) + 64m + 1024*(t>>6)].
        // 256 B contiguous per wave-instruction; stores are fire-and-forget
        // (no barrier after them anymore).
        {
            float* orw = out + (size_t)row * FWHT_N;
            const int baseO = (t & 63) + 1024 * (t >> 6);
#pragma unroll
            for (int m = 0; m < 16; ++m) {
                orw[baseO + 64 * m] = a[m] * scale;
            }
        }

        p ^= 1;
    }
}

extern "C" void kernel_launch(void* const* d_in, const int* in_sizes, int n_in,
                              void* d_out, int out_size, void* d_ws, size_t ws_size,
                              hipStream_t stream) {
    const float* x = (const float*)d_in[0];
    const float* s = (const float*)d_in[1];
    float* out = (float*)d_out;
    const int rows = in_sizes[0] / FWHT_N;  // 16384
    const int blocks = rows < MAX_BLOCKS ? rows : MAX_BLOCKS;
    fwht_rows_kernel<<<blocks, TPB, 0, stream>>>(x, s, out, rows);
}